// Round 7
// baseline (286.409 us; speedup 1.0000x reference)
//
#include <hip/hip_runtime.h>

#define LBL 32
#define NPIX (736 * 736)   // 541696
#define NQ (NPIX / 4)      // 135424 = 529 * 256 float4-quads per batch
#define NB 529             // blocks per batch (1 quad per thread)
#define BATCH 8
#define DELTA_AGG 0.5f
#define DELTA_DIS 1.5f
#define REG_W 0.001f

// ws layout (float indices), ~42.8 MB total — all slots plain-stored before read:
//  ce:    [0, +8*NPIX*2)          bf16 e[4] per px, interleaved (8 B/px)
//  lab:   [LAB_BASE, +8*NPIX/4)   uint8 masked label per px
//  partA: [PA_BASE, +8*529*192)   per (batch,block): cnt_k[32], sum[128], cnt_a[32]
//  red:   [RED_BASE, +8*256)      per batch: cnt_k[32], mean[128], cnt_a[32] @160
//  partC: [PC_BASE, +8*529*32)    per (batch,block): val[32]
#define CE_BASE 0
#define LAB_BASE (BATCH * NPIX * 2)            // 8667136
#define PA_BASE (LAB_BASE + BATCH * NPIX / 4)  // 9750528
#define RED_BASE (PA_BASE + BATCH * NB * 192)  // 10563072
#define PC_BASE (RED_BASE + BATCH * 256)       // 10565120
// end: PC_BASE + 8*529*32 = 10700544 floats = 42802176 bytes

__device__ __forceinline__ unsigned short f2bf(float f) {  // RTNE
  unsigned int u = __float_as_uint(f);
  unsigned int r = u + 0x7FFFu + ((u >> 16) & 1u);
  return (unsigned short)(r >> 16);
}
__device__ __forceinline__ float bfl(unsigned int w) {
  return __uint_as_float(w << 16);
}
__device__ __forceinline__ float bfh(unsigned int w) {
  return __uint_as_float(w & 0xFFFF0000u);
}

// ===== Pass A: kernel-region sums + both histograms + compact spill =========
__global__ __launch_bounds__(256) void kA(
    const float* __restrict__ emb, const int* __restrict__ inst,
    const float* __restrict__ kern, const float* __restrict__ mask,
    float* __restrict__ ws) {
  const int b = blockIdx.y;
  const int t = threadIdx.x;
  __shared__ float s_cnt[LBL];   // [0] is the "saw label 0" flag
  __shared__ float s_sum[LBL * 4];
  __shared__ float s_cnta[LBL];  // mask-only histogram (cnt_a), label>0 used
  if (t < LBL) { s_cnt[t] = 0.f; s_cnta[t] = 0.f; }
  if (t < LBL * 4) s_sum[t] = 0.f;
  __syncthreads();

  const long base = (long)b * NPIX;
  const int q = blockIdx.x * 256 + t;  // one quad per thread
  const int4 iv = ((const int4*)(inst + base))[q];
  const float4 kv = ((const float4*)(kern + base))[q];
  const float4 mv = ((const float4*)(mask + base))[q];
  const float* eb = emb + (long)b * 4 * NPIX;
  const float4 e0 = ((const float4*)(eb))[q];
  const float4 e1 = ((const float4*)(eb + NPIX))[q];
  const float4 e2 = ((const float4*)(eb + 2 * NPIX))[q];
  const float4 e3 = ((const float4*)(eb + 3 * NPIX))[q];

  const int labs[4] = {iv.x, iv.y, iv.z, iv.w};
  const float ks[4] = {kv.x, kv.y, kv.z, kv.w};
  const float ms[4] = {mv.x, mv.y, mv.z, mv.w};
  const float c0[4] = {e0.x, e0.y, e0.z, e0.w};
  const float c1[4] = {e1.x, e1.y, e1.z, e1.w};
  const float c2[4] = {e2.x, e2.y, e2.z, e2.w};
  const float c3[4] = {e3.x, e3.y, e3.z, e3.w};

  bool has0 = false;
  unsigned int labw = 0;
  union { unsigned short us[16]; uint4 v[2]; } pk;
#pragma unroll
  for (int j = 0; j < 4; j++) {
    const bool m = ms[j] > 0.5f;
    const int li = m ? labs[j] : 0;                 // mask-only label
    const int lk = (m && ks[j] > 0.5f) ? labs[j] : 0;  // kernel-region label
    labw |= ((unsigned int)li) << (8 * j);
    pk.us[j * 4 + 0] = f2bf(c0[j]);
    pk.us[j * 4 + 1] = f2bf(c1[j]);
    pk.us[j * 4 + 2] = f2bf(c2[j]);
    pk.us[j * 4 + 3] = f2bf(c3[j]);
    if (li > 0) atomicAdd(&s_cnta[li], 1.0f);
    if (lk > 0) {
      atomicAdd(&s_cnt[lk], 1.0f);
      atomicAdd(&s_sum[lk * 4 + 0], c0[j]);
      atomicAdd(&s_sum[lk * 4 + 1], c1[j]);
      atomicAdd(&s_sum[lk * 4 + 2], c2[j]);
      atomicAdd(&s_sum[lk * 4 + 3], c3[j]);
    } else {
      has0 = true;
    }
  }
  // compact spill: 32 B of bf16 e + 4 B labels per thread, fully coalesced
  const size_t recq = (size_t)b * NQ + q;
  uint4* cep = (uint4*)(ws + CE_BASE);
  cep[recq * 2] = pk.v[0];
  cep[recq * 2 + 1] = pk.v[1];
  ((unsigned int*)(ws + LAB_BASE))[recq] = labw;

  if (has0) s_cnt[0] = 1.0f;  // benign race: all writers store 1
  __syncthreads();
  float* po = ws + PA_BASE + (size_t)(b * NB + blockIdx.x) * 192;
  if (t < 192)
    po[t] = (t < 32) ? s_cnt[t] : (t < 160 ? s_sum[t - 32] : s_cnta[t - 160]);
}

// ===== Reduce A partials -> cnt_k, means, cnt_a (one block per batch) =======
__global__ __launch_bounds__(256) void kB(float* __restrict__ ws) {
  const int b = blockIdx.x, t = threadIdx.x;
  const float* pa = ws + PA_BASE + (size_t)b * NB * 192;
  // sums: 128 elems x 2 group-chunks
  float s = 0.f;
  {
    const int cs = t >> 7, es = t & 127;
    const float* p = pa + 32 + es;
    for (int g = cs; g < NB; g += 2) s += p[(size_t)g * 192];
  }
  // counts: 64 elems (cnt_k[0,32) + cnt_a[160,192)) x 4 group-chunks
  float sc = 0.f;
  {
    const int cc = t >> 6, ec = t & 63;
    const float* p = pa + (ec < 32 ? ec : 128 + ec);
    for (int g = cc; g < NB; g += 4) sc += p[(size_t)g * 192];
  }
  __shared__ float redS[256], redC[256], ctot[64];
  redS[t] = s;
  redC[t] = sc;
  __syncthreads();
  float* rd = ws + RED_BASE + b * 256;
  if (t < 64) {
    const float c = redC[t] + redC[64 + t] + redC[128 + t] + redC[192 + t];
    ctot[t] = c;
    rd[(t < 32) ? t : 128 + t] = c;  // cnt_k -> rd[0..31]; cnt_a -> rd[160..191]
  }
  __syncthreads();
  if (t < 128) {
    const int l = t >> 2;
    const float stot = redS[t] + redS[128 + t];
    rd[32 + t] = (l == 0) ? 0.f : stot / fmaxf(ctot[l], 1.0f);  // mean
  }
}

// ===== Pass C: aggregation loss sums from the compact spill =================
__global__ __launch_bounds__(256) void kC(float* __restrict__ ws) {
  const int b = blockIdx.y;
  const int t = threadIdx.x;
  __shared__ float s_mean[LBL * 4];
  __shared__ float s_val[LBL];
  const float* rd = ws + RED_BASE + b * 256;
  if (t < LBL * 4) s_mean[t] = rd[32 + t];
  if (t < LBL) s_val[t] = 0.f;
  __syncthreads();

  const int q = blockIdx.x * 256 + t;
  const size_t recq = (size_t)b * NQ + q;
  const uint4* cep = (const uint4*)(ws + CE_BASE);
  const uint4 r0 = cep[recq * 2];
  const uint4 r1 = cep[recq * 2 + 1];
  const unsigned int labw = ((const unsigned int*)(ws + LAB_BASE))[recq];

  const unsigned int wlo[4] = {r0.x, r0.z, r1.x, r1.z};
  const unsigned int whi[4] = {r0.y, r0.w, r1.y, r1.w};
#pragma unroll
  for (int j = 0; j < 4; j++) {
    const int li = (labw >> (8 * j)) & 0xFF;
    if (li > 0) {  // label 0 excluded from l_agg (nz mask)
      const float d0 = bfl(wlo[j]) - s_mean[li * 4 + 0];
      const float d1 = bfh(wlo[j]) - s_mean[li * 4 + 1];
      const float d2 = bfl(whi[j]) - s_mean[li * 4 + 2];
      const float d3 = bfh(whi[j]) - s_mean[li * 4 + 3];
      const float sq = d0 * d0 + d1 * d1 + d2 * d2 + d3 * d3;
      const float dist = (sq > 0.f) ? sqrtf(sq) : 0.f;
      const float tt = fmaxf(dist - DELTA_AGG, 0.f);
      atomicAdd(&s_val[li], logf(fmaf(tt, tt, 1.0f)));
    }
  }
  __syncthreads();
  float* po = ws + PC_BASE + (size_t)(b * NB + blockIdx.x) * 32;
  if (t < 32) po[t] = s_val[t];
}

// ===== Reduce C + finalize (one block per batch) ============================
__global__ __launch_bounds__(256) void kD(const float* __restrict__ ws,
                                          float* __restrict__ out) {
  const int b = blockIdx.x;
  const int t = threadIdx.x;
  const float* pc = ws + PC_BASE + (size_t)b * NB * 32;
  float s = 0.f;
  {
    const int c8 = t >> 5, e = t & 31;
    const float* p = pc + e;
    for (int g = c8; g < NB; g += 8) s += p[(size_t)g * 32];
  }
  __shared__ float redV[256];
  redV[t] = s;
  const float* rd = ws + RED_BASE + b * 256;
  __shared__ float sm[LBL * 4];
  __shared__ float scc[LBL];  // cnt_k
  __shared__ float sca[LBL];  // cnt_a
  if (t < 128) sm[t] = rd[32 + t];
  else if (t < 160) scc[t - 128] = rd[t - 128];
  else if (t < 192) sca[t - 160] = rd[t];  // rd[160..191]
  __syncthreads();
  __shared__ float sv[LBL];
  if (t < 32) {
    float v = 0.f;
#pragma unroll
    for (int k = 0; k < 8; k++) v += redV[k * 32 + t];
    sv[t] = v;
  }
  __syncthreads();

  if (t < 64) {  // wave 0 only
    const int lane = t;
    const bool pres = (lane < LBL) && (scc[lane & 31] > 0.f);
    const unsigned long long bal_p = __ballot(pres);
    const int num_instance = __popcll(bal_p);
    const bool nz = pres && (lane > 0);
    const unsigned long long bal_nz = __ballot(nz);

    float agg = 0.f;
    if (nz) agg = sv[lane] / fmaxf(sca[lane], 1.0f);

    float reg = 0.f;
    if (pres) {
      float sq = 0.f;
#pragma unroll
      for (int d = 0; d < 4; d++) sq += sm[lane * 4 + d] * sm[lane * 4 + d];
      const float nrm = (sq > 0.f) ? sqrtf(sq) : 0.f;
      reg = logf(nrm + 1.0f);
    }

    float dis = 0.f, npair = 0.f;
    for (int pi = lane; pi < LBL * LBL; pi += 64) {
      const int i = pi >> 5, j = pi & 31;
      if (i != j && ((bal_nz >> i) & 1ull) && ((bal_nz >> j) & 1ull)) {
        float sq = 0.f;
#pragma unroll
        for (int d = 0; d < 4; d++) {
          const float df = sm[i * 4 + d] - sm[j * 4 + d];
          sq += df * df;
        }
        const float pdist = (sq > 0.f) ? sqrtf(sq) : 0.f;
        const float tt = fmaxf(2.0f * DELTA_DIS - pdist, 0.f);
        dis += logf(fmaf(tt, tt, 1.0f));
        npair += 1.0f;
      }
    }

#pragma unroll
    for (int o = 32; o > 0; o >>= 1) {
      agg += __shfl_down(agg, o);
      reg += __shfl_down(reg, o);
      dis += __shfl_down(dis, o);
      npair += __shfl_down(npair, o);
    }

    if (lane == 0) {
      const float l_agg = agg / fmaxf((float)(num_instance - 1), 1.0f);
      const float l_dis = (num_instance > 2) ? dis / fmaxf(npair, 1.0f) : 0.f;
      const float l_reg = reg / fmaxf((float)num_instance, 1.0f) * REG_W;
      const float loss = l_agg + l_dis + l_reg;
      out[b] = (num_instance <= 1) ? 0.f : loss;
    }
  }
}

extern "C" void kernel_launch(void* const* d_in, const int* in_sizes, int n_in,
                              void* d_out, int out_size, void* d_ws,
                              size_t ws_size, hipStream_t stream) {
  const float* emb = (const float*)d_in[0];
  const int* instance = (const int*)d_in[1];
  const float* kern = (const float*)d_in[2];
  const float* mask = (const float*)d_in[3];
  float* out = (float*)d_out;
  float* ws = (float*)d_ws;

  dim3 grid(NB, BATCH);  // 4232 blocks, one float4-quad per thread
  kA<<<grid, 256, 0, stream>>>(emb, instance, kern, mask, ws);
  kB<<<BATCH, 256, 0, stream>>>(ws);
  kC<<<grid, 256, 0, stream>>>(ws);
  kD<<<BATCH, 256, 0, stream>>>(ws, out);
}

// Round 8
// 185.052 us; speedup vs baseline: 1.5477x; 1.5477x over previous
//
#include <hip/hip_runtime.h>

#define LBL 32
#define NPIX (736 * 736)   // 541696
#define NQ (NPIX / 4)      // 135424 = 529 * 256 float4-quads per batch
#define NB 529             // blocks per batch (1 quad per thread)
#define BATCH 8
#define DELTA_AGG 0.5f
#define DELTA_DIS 1.5f
#define REG_W 0.001f

// ws layout (float indices) — all slots plain-stored before read, no memset:
//  ce:    [0, +8*NPIX*2)          bf16 e[4] per px, interleaved (8 B/px)
//  lab:   [LAB_BASE, +8*NPIX/4)   uint8 masked label per px
//  partA: [PA_BASE, +8*192*NB)    TRANSPOSED per batch: [elem 0..191][block 0..NB)
//         elem: 0..31 cnt_k ([0]=saw-label-0 flag), 32..159 sum, 160..191 cnt_a
//  red:   [RED_BASE, +8*256)      per batch RAW TOTALS: cnt_k[32], sumtot[128], cnt_a[32]
//  partC: [PC_BASE, +8*32*NB)     TRANSPOSED per batch: [elem 0..31][block]
#define CE_BASE 0
#define LAB_BASE (BATCH * NPIX * 2)            // 8667136
#define PA_BASE (LAB_BASE + BATCH * NPIX / 4)  // 9750528
#define RED_BASE (PA_BASE + BATCH * 192 * NB)  // 10563072
#define PC_BASE (RED_BASE + BATCH * 256)       // 10565120
// end: PC_BASE + 8*32*529 = 10700544 floats = 42.8 MB

__device__ __forceinline__ unsigned short f2bf(float f) {  // RTNE
  unsigned int u = __float_as_uint(f);
  unsigned int r = u + 0x7FFFu + ((u >> 16) & 1u);
  return (unsigned short)(r >> 16);
}
__device__ __forceinline__ float bfl(unsigned int w) {
  return __uint_as_float(w << 16);
}
__device__ __forceinline__ float bfh(unsigned int w) {
  return __uint_as_float(w & 0xFFFF0000u);
}

// ===== Pass A: kernel-region sums + both histograms + compact spill =========
__global__ __launch_bounds__(256) void kA(
    const float* __restrict__ emb, const int* __restrict__ inst,
    const float* __restrict__ kern, const float* __restrict__ mask,
    float* __restrict__ ws) {
  const int b = blockIdx.y;
  const int t = threadIdx.x;
  __shared__ float s_cnt[LBL];   // [0] is the "saw label 0" flag
  __shared__ float s_sum[LBL * 4];
  __shared__ float s_cnta[LBL];  // mask-only histogram (cnt_a)
  if (t < LBL) { s_cnt[t] = 0.f; s_cnta[t] = 0.f; }
  if (t < LBL * 4) s_sum[t] = 0.f;
  __syncthreads();

  const long base = (long)b * NPIX;
  const int q = blockIdx.x * 256 + t;  // one quad per thread
  const int4 iv = ((const int4*)(inst + base))[q];
  const float4 kv = ((const float4*)(kern + base))[q];
  const float4 mv = ((const float4*)(mask + base))[q];
  const float* eb = emb + (long)b * 4 * NPIX;
  const float4 e0 = ((const float4*)(eb))[q];
  const float4 e1 = ((const float4*)(eb + NPIX))[q];
  const float4 e2 = ((const float4*)(eb + 2 * NPIX))[q];
  const float4 e3 = ((const float4*)(eb + 3 * NPIX))[q];

  const int labs[4] = {iv.x, iv.y, iv.z, iv.w};
  const float ks[4] = {kv.x, kv.y, kv.z, kv.w};
  const float ms[4] = {mv.x, mv.y, mv.z, mv.w};
  const float c0[4] = {e0.x, e0.y, e0.z, e0.w};
  const float c1[4] = {e1.x, e1.y, e1.z, e1.w};
  const float c2[4] = {e2.x, e2.y, e2.z, e2.w};
  const float c3[4] = {e3.x, e3.y, e3.z, e3.w};

  bool has0 = false;
  unsigned int labw = 0;
  union { unsigned short us[16]; uint4 v[2]; } pk;
#pragma unroll
  for (int j = 0; j < 4; j++) {
    const bool m = ms[j] > 0.5f;
    const int li = m ? labs[j] : 0;                    // mask-only label
    const int lk = (m && ks[j] > 0.5f) ? labs[j] : 0;  // kernel-region label
    labw |= ((unsigned int)li) << (8 * j);
    pk.us[j * 4 + 0] = f2bf(c0[j]);
    pk.us[j * 4 + 1] = f2bf(c1[j]);
    pk.us[j * 4 + 2] = f2bf(c2[j]);
    pk.us[j * 4 + 3] = f2bf(c3[j]);
    if (li > 0) atomicAdd(&s_cnta[li], 1.0f);
    if (lk > 0) {
      atomicAdd(&s_cnt[lk], 1.0f);
      atomicAdd(&s_sum[lk * 4 + 0], c0[j]);
      atomicAdd(&s_sum[lk * 4 + 1], c1[j]);
      atomicAdd(&s_sum[lk * 4 + 2], c2[j]);
      atomicAdd(&s_sum[lk * 4 + 3], c3[j]);
    } else {
      has0 = true;
    }
  }
  // compact spill: 32 B bf16 e + 4 B labels per thread, fully coalesced
  const size_t recq = (size_t)b * NQ + q;
  uint4* cep = (uint4*)(ws + CE_BASE);
  cep[recq * 2] = pk.v[0];
  cep[recq * 2 + 1] = pk.v[1];
  ((unsigned int*)(ws + LAB_BASE))[recq] = labw;

  if (has0) s_cnt[0] = 1.0f;  // benign race: all writers store 1
  __syncthreads();
  // TRANSPOSED partial store: elem-major, block index contiguous per elem
  if (t < 192) {
    const float v = (t < 32) ? s_cnt[t] : (t < 160 ? s_sum[t - 32] : s_cnta[t - 160]);
    ws[PA_BASE + ((size_t)b * 192 + t) * NB + blockIdx.x] = v;
  }
}

// ===== Reduce A: one wave per (batch, elem) column — coalesced ==============
__global__ __launch_bounds__(256) void kB(float* __restrict__ ws) {
  const int b = blockIdx.y;
  const int col = blockIdx.x * 4 + (threadIdx.x >> 6);  // 48 blocks x 4 waves = 192
  const int lane = threadIdx.x & 63;
  const float* p = ws + PA_BASE + ((size_t)b * 192 + col) * NB;
  float s = 0.f;
  for (int g = lane; g < NB; g += 64) s += p[g];  // 9 coalesced loads
#pragma unroll
  for (int o = 32; o > 0; o >>= 1) s += __shfl_down(s, o);
  if (lane == 0) ws[RED_BASE + b * 256 + col] = s;  // raw totals
}

// ===== Pass C: aggregation loss sums from the compact spill =================
__global__ __launch_bounds__(256) void kC(float* __restrict__ ws) {
  const int b = blockIdx.y;
  const int t = threadIdx.x;
  __shared__ float s_mean[LBL * 4];
  __shared__ float s_val[LBL];
  const float* rd = ws + RED_BASE + b * 256;
  if (t < LBL * 4) {
    const int l = t >> 2;
    s_mean[t] = (l == 0) ? 0.f : rd[32 + t] / fmaxf(rd[l], 1.0f);
  }
  if (t < LBL) s_val[t] = 0.f;
  __syncthreads();

  const int q = blockIdx.x * 256 + t;
  const size_t recq = (size_t)b * NQ + q;
  const uint4* cep = (const uint4*)(ws + CE_BASE);
  const uint4 r0 = cep[recq * 2];
  const uint4 r1 = cep[recq * 2 + 1];
  const unsigned int labw = ((const unsigned int*)(ws + LAB_BASE))[recq];

  const unsigned int wlo[4] = {r0.x, r0.z, r1.x, r1.z};
  const unsigned int whi[4] = {r0.y, r0.w, r1.y, r1.w};
#pragma unroll
  for (int j = 0; j < 4; j++) {
    const int li = (labw >> (8 * j)) & 0xFF;
    if (li > 0) {  // label 0 excluded from l_agg (nz mask)
      const float d0 = bfl(wlo[j]) - s_mean[li * 4 + 0];
      const float d1 = bfh(wlo[j]) - s_mean[li * 4 + 1];
      const float d2 = bfl(whi[j]) - s_mean[li * 4 + 2];
      const float d3 = bfh(whi[j]) - s_mean[li * 4 + 3];
      const float sq = d0 * d0 + d1 * d1 + d2 * d2 + d3 * d3;
      const float dist = (sq > 0.f) ? sqrtf(sq) : 0.f;
      const float tt = fmaxf(dist - DELTA_AGG, 0.f);
      atomicAdd(&s_val[li], logf(fmaf(tt, tt, 1.0f)));
    }
  }
  __syncthreads();
  // TRANSPOSED partial store
  if (t < 32) ws[PC_BASE + ((size_t)b * 32 + t) * NB + blockIdx.x] = s_val[t];
}

// ===== Reduce C + finalize (one 1024-thread block per batch) ================
__global__ __launch_bounds__(1024) void kD(const float* __restrict__ ws,
                                           float* __restrict__ out) {
  const int b = blockIdx.x;
  const int t = threadIdx.x;
  const int col = t >> 5, sub = t & 31;  // 32 cols x 32 chunks
  const float* p = ws + PC_BASE + ((size_t)b * 32 + col) * NB;
  float s = 0.f;
  for (int g = sub; g < NB; g += 32) s += p[g];  // 17 coalesced loads
  __shared__ float red[LBL][33];
  red[col][sub] = s;

  const float* rd = ws + RED_BASE + b * 256;
  __shared__ float sm[LBL * 4];
  __shared__ float scc[LBL];  // cnt_k
  __shared__ float sca[LBL];  // cnt_a
  if (t >= 512 && t < 640) {
    const int e = t - 512, l = e >> 2;
    sm[e] = (l == 0) ? 0.f : rd[32 + e] / fmaxf(rd[l], 1.0f);
  } else if (t >= 640 && t < 672) {
    scc[t - 640] = rd[t - 640];
  } else if (t >= 672 && t < 704) {
    sca[t - 672] = rd[160 + (t - 672)];
  }
  __syncthreads();
  __shared__ float sv[LBL];
  if (t < 32) {
    float v = 0.f;
#pragma unroll
    for (int k = 0; k < 32; k++) v += red[t][k];
    sv[t] = v;
  }
  __syncthreads();

  if (t < 64) {  // wave 0 only
    const int lane = t;
    const bool pres = (lane < LBL) && (scc[lane & 31] > 0.f);
    const unsigned long long bal_p = __ballot(pres);
    const int num_instance = __popcll(bal_p);
    const bool nz = pres && (lane > 0);
    const unsigned long long bal_nz = __ballot(nz);

    float agg = 0.f;
    if (nz) agg = sv[lane] / fmaxf(sca[lane], 1.0f);

    float reg = 0.f;
    if (pres) {
      float sq = 0.f;
#pragma unroll
      for (int d = 0; d < 4; d++) sq += sm[lane * 4 + d] * sm[lane * 4 + d];
      const float nrm = (sq > 0.f) ? sqrtf(sq) : 0.f;
      reg = logf(nrm + 1.0f);
    }

    float dis = 0.f, npair = 0.f;
    for (int pi = lane; pi < LBL * LBL; pi += 64) {
      const int i = pi >> 5, j = pi & 31;
      if (i != j && ((bal_nz >> i) & 1ull) && ((bal_nz >> j) & 1ull)) {
        float sq = 0.f;
#pragma unroll
        for (int d = 0; d < 4; d++) {
          const float df = sm[i * 4 + d] - sm[j * 4 + d];
          sq += df * df;
        }
        const float pdist = (sq > 0.f) ? sqrtf(sq) : 0.f;
        const float tt = fmaxf(2.0f * DELTA_DIS - pdist, 0.f);
        dis += logf(fmaf(tt, tt, 1.0f));
        npair += 1.0f;
      }
    }

#pragma unroll
    for (int o = 32; o > 0; o >>= 1) {
      agg += __shfl_down(agg, o);
      reg += __shfl_down(reg, o);
      dis += __shfl_down(dis, o);
      npair += __shfl_down(npair, o);
    }

    if (lane == 0) {
      const float l_agg = agg / fmaxf((float)(num_instance - 1), 1.0f);
      const float l_dis = (num_instance > 2) ? dis / fmaxf(npair, 1.0f) : 0.f;
      const float l_reg = reg / fmaxf((float)num_instance, 1.0f) * REG_W;
      const float loss = l_agg + l_dis + l_reg;
      out[b] = (num_instance <= 1) ? 0.f : loss;
    }
  }
}

extern "C" void kernel_launch(void* const* d_in, const int* in_sizes, int n_in,
                              void* d_out, int out_size, void* d_ws,
                              size_t ws_size, hipStream_t stream) {
  const float* emb = (const float*)d_in[0];
  const int* instance = (const int*)d_in[1];
  const float* kern = (const float*)d_in[2];
  const float* mask = (const float*)d_in[3];
  float* out = (float*)d_out;
  float* ws = (float*)d_ws;

  dim3 gridA(NB, BATCH);  // 4232 blocks, one float4-quad per thread
  kA<<<gridA, 256, 0, stream>>>(emb, instance, kern, mask, ws);
  dim3 gridB(48, BATCH);  // one wave per (batch, elem) column
  kB<<<gridB, 256, 0, stream>>>(ws);
  kC<<<gridA, 256, 0, stream>>>(ws);
  kD<<<BATCH, 1024, 0, stream>>>(ws, out);
}